// Round 3
// baseline (171.711 us; speedup 1.0000x reference)
//
#include <hip/hip_runtime.h>
#include <hip/hip_bf16.h>

typedef __attribute__((ext_vector_type(8))) short short8;
typedef __attribute__((ext_vector_type(4))) float f32x4;

#define L2E 1.44269504088896340736f

__device__ __forceinline__ float ipow(float x, int e) {
    float r = 1.f;
    for (int i = 0; i < e; ++i) r *= x;
    return r;
}

// ---------------------------------------------------------------------------
// prep_w: build the bf16 fragment-ordered image of w in d_ws (64 KB).
// Thread i reads w[i] COALESCED (i = n*32 + c) and scatters the bf16 to its
// fragment slot: frag=(chg*2+kk)*2+ct, lane l, elem j with
//   n = chg*64 + kk*32 + 8*(l>>4) + j,  c = ct*16 + (l&15)
// ---------------------------------------------------------------------------
__global__ void prep_w(const float* __restrict__ w, unsigned short* __restrict__ img)
{
    int i = blockIdx.x * 256 + threadIdx.x;      // 128 blocks x 256 = 32768
    int n = i >> 5, c = i & 31;
    int chg = n >> 6, kk = (n >> 5) & 1, ct = c >> 4;
    int l = (((n >> 3) & 3) << 4) | (c & 15);
    int j = n & 7;
    int dst = ((chg * 2 + kk) * 2 + ct) * 512 + l * 8 + j;
    __hip_bfloat16 h = __float2bfloat16(w[i]);
    img[dst] = *(unsigned short*)&h;
}

// ---------------------------------------------------------------------------
// Main: Q=32768, N=1024, C=32. 1024 blocks x 256 threads (4 waves).
// Block covers 32 q-rows. wave wv: row-group rg=wv>>1 (16 rows), n-half=wv&1.
// Lane l: row m=l&15, k-quad kq=l>>4. exp values are computed DIRECTLY in
// MFMA A-fragment layout (no LDS transpose). B-fragments stream from the
// L2-resident wimg, software-pipelined one u-iteration ahead. 4-point
// sub-groups keep live VGPRs ~90 (no spill under the 128-reg cap).
// ---------------------------------------------------------------------------
__global__ __launch_bounds__(256, 4)
void rbf_main(const float* __restrict__ q_pos,
              const float* __restrict__ data_pos,
              const float* __restrict__ cmat,
              const int* __restrict__ poly_power,
              const unsigned short* __restrict__ wimg,
              float* __restrict__ out_val,    // [Q,32]
              float* __restrict__ out_kd,     // [Q,1024]
              float* __restrict__ out_poly)   // [Q,4]
{
    const int t  = threadIdx.x;
    const int l  = t & 63;
    const int wv = t >> 6;
    const int rg   = wv >> 1;
    const int half = wv & 1;
    const int q0 = blockIdx.x * 32 + rg * 16;
    const int m  = l & 15;
    const int kq = l >> 4;
    const int nbase = half * 512;

    __shared__ float s_sum[2][2][16];
    __shared__ float s_acc[2][64][8];

    const float qx = q_pos[(q0 + m) * 3 + 0];
    const float qy = q_pos[(q0 + m) * 3 + 1];
    const float qz = q_pos[(q0 + m) * 3 + 2];

    // ---- out_poly: 128 threads/block cover this block's 32 rows x 4 ----
    if (t < 128) {
        int q = blockIdx.x * 32 + (t >> 2), p = t & 3;
        int e0 = poly_power[p * 3], e1 = poly_power[p * 3 + 1], e2 = poly_power[p * 3 + 2];
        float x = q_pos[q * 3], y = q_pos[q * 3 + 1], z = q_pos[q * 3 + 2];
        out_poly[q * 4 + p] = ipow(x, e0) * ipow(y, e1) * ipow(z, e2);
    }

    // ---- phase 1: partial row-sum of exp(-r^2), 4-point groups ----
    float s = 0.f;
    for (int u = 0; u < 16; ++u) {
        int p0 = nbase + 32 * u + 8 * kq;
        const float* dp = data_pos + 3 * p0;
#pragma unroll
        for (int h = 0; h < 2; ++h) {
            float f[12];
#pragma unroll
            for (int i = 0; i < 3; ++i)
                *(float4*)&f[i * 4] = *(const float4*)(dp + h * 12 + i * 4);
#pragma unroll
            for (int j = 0; j < 4; ++j) {
                float dx = qx - f[3 * j], dy = qy - f[3 * j + 1], dz = qz - f[3 * j + 2];
                float r2 = dx * dx + dy * dy + dz * dz;
                s += __builtin_amdgcn_exp2f(r2 * (-L2E));
            }
        }
    }
    s += __shfl_xor(s, 16);
    s += __shfl_xor(s, 32);
    if (l < 16) s_sum[rg][half][m] = s;
    __syncthreads();
    const float invm = 1.0f / (s_sum[rg][0][m] + s_sum[rg][1][m]);

    // ---- phase 2: recompute in fragment order, MFMA, dense-ish stores ----
    f32x4 acc0 = {0.f, 0.f, 0.f, 0.f};
    f32x4 acc1 = {0.f, 0.f, 0.f, 0.f};
    const size_t kdrow = (size_t)(q0 + m) * 1024;
    const unsigned short* wbase = wimg + (half * 16) * 1024 + l * 8;

    // software-pipelined B fragments (1 iteration ahead)
    short8 b0 = *(const short8*)(wbase);
    short8 b1 = *(const short8*)(wbase + 512);

    for (int u = 0; u < 16; ++u) {
        int un = (u < 15) ? (u + 1) : 15;
        short8 p0f = *(const short8*)(wbase + un * 1024);
        short8 p1f = *(const short8*)(wbase + un * 1024 + 512);

        int p0 = nbase + 32 * u + 8 * kq;
        const float* dp = data_pos + 3 * p0;

        union { short8 v; __hip_bfloat162 h[4]; } a;
#pragma unroll
        for (int h = 0; h < 2; ++h) {
            float f[12];
#pragma unroll
            for (int i = 0; i < 3; ++i)
                *(float4*)&f[i * 4] = *(const float4*)(dp + h * 12 + i * 4);
            float v0, v1, v2, v3;
            {
                float dx, dy, dz, r2;
                dx = qx - f[0];  dy = qy - f[1];  dz = qz - f[2];
                r2 = dx * dx + dy * dy + dz * dz;
                v0 = __builtin_amdgcn_exp2f(r2 * (-L2E)) * invm;
                dx = qx - f[3];  dy = qy - f[4];  dz = qz - f[5];
                r2 = dx * dx + dy * dy + dz * dz;
                v1 = __builtin_amdgcn_exp2f(r2 * (-L2E)) * invm;
                dx = qx - f[6];  dy = qy - f[7];  dz = qz - f[8];
                r2 = dx * dx + dy * dy + dz * dz;
                v2 = __builtin_amdgcn_exp2f(r2 * (-L2E)) * invm;
                dx = qx - f[9];  dy = qy - f[10]; dz = qz - f[11];
                r2 = dx * dx + dy * dy + dz * dz;
                v3 = __builtin_amdgcn_exp2f(r2 * (-L2E)) * invm;
            }
            float2 p01; p01.x = v0; p01.y = v1;
            float2 p23; p23.x = v2; p23.y = v3;
            a.h[h * 2]     = __float22bfloat162_rn(p01);
            a.h[h * 2 + 1] = __float22bfloat162_rn(p23);
            float4 st; st.x = v0; st.y = v1; st.z = v2; st.w = v3;
            *(float4*)(out_kd + kdrow + p0 + 4 * h) = st;
        }

        acc0 = __builtin_amdgcn_mfma_f32_16x16x32_bf16(a.v, b0, acc0, 0, 0, 0);
        acc1 = __builtin_amdgcn_mfma_f32_16x16x32_bf16(a.v, b1, acc1, 0, 0, 0);
        b0 = p0f;
        b1 = p1f;
    }

    // ---- combine accumulators across the n-half wave pair ----
    if (half == 1) {
#pragma unroll
        for (int i = 0; i < 4; ++i) {
            s_acc[rg][l][i]     = acc0[i];
            s_acc[rg][l][i + 4] = acc1[i];
        }
    }
    __syncthreads();
    if (half == 0) {
#pragma unroll
        for (int i = 0; i < 4; ++i) {
            acc0[i] += s_acc[rg][l][i];
            acc1[i] += s_acc[rg][l][i + 4];
        }
        int pw[12];
#pragma unroll
        for (int i = 0; i < 12; ++i) pw[i] = poly_power[i];
        float cp0[4], cp1[4];
#pragma unroll
        for (int p = 0; p < 4; ++p) {
            cp0[p] = cmat[p * 32 + m];
            cp1[p] = cmat[p * 32 + 16 + m];
        }
#pragma unroll
        for (int r = 0; r < 4; ++r) {
            int row = kq * 4 + r;                  // D row = (l>>4)*4 + reg
            int q = q0 + row;
            float x = q_pos[q * 3], y = q_pos[q * 3 + 1], z = q_pos[q * 3 + 2];
            float cv0 = 0.f, cv1 = 0.f;
#pragma unroll
            for (int p = 0; p < 4; ++p) {
                float pv = ipow(x, pw[p * 3]) * ipow(y, pw[p * 3 + 1]) * ipow(z, pw[p * 3 + 2]);
                cv0 += cp0[p] * pv;
                cv1 += cp1[p] * pv;
            }
            out_val[q * 32 + m]      = acc0[r] + cv0;
            out_val[q * 32 + 16 + m] = acc1[r] + cv1;
        }
    }
}

extern "C" void kernel_launch(void* const* d_in, const int* in_sizes, int n_in,
                              void* d_out, int out_size, void* d_ws, size_t ws_size,
                              hipStream_t stream) {
    const float* q_pos      = (const float*)d_in[0];
    const float* data_pos   = (const float*)d_in[1];
    const float* w          = (const float*)d_in[2];
    const float* cmat       = (const float*)d_in[3];
    const int*   poly_power = (const int*)d_in[4];

    const int Q = in_sizes[0] / 3;               // 32768
    float* out      = (float*)d_out;
    float* out_val  = out;                       // [Q,32]
    float* out_kd   = out + (size_t)Q * 32;      // [Q,1024]
    float* out_poly = out_kd + (size_t)Q * 1024; // [Q,4]

    unsigned short* wimg = (unsigned short*)d_ws;    // 64 KB fragment image

    prep_w<<<128, 256, 0, stream>>>(w, wimg);
    rbf_main<<<Q / 32, 256, 0, stream>>>(q_pos, data_pos, cmat, poly_power, wimg,
                                         out_val, out_kd, out_poly);
}